// Round 4
// baseline (115.930 us; speedup 1.0000x reference)
//
#include <hip/hip_runtime.h>
#include <math.h>

#define DIM 64
#define HEADS 4
#define BB 8
#define QQ 128
#define VV 128
#define NN (BB*QQ)   // 1024

typedef float f2 __attribute__((ext_vector_type(2)));
typedef float f4 __attribute__((ext_vector_type(4)));

// ---- DPP helpers (VALU, no DS); CTRL is a compile-time template constant ----
template <int CTRL>
__device__ __forceinline__ float dppf(float x) {
    return __int_as_float(__builtin_amdgcn_update_dpp(
        0, __float_as_int(x), CTRL, 0xF, 0xF, true));
}
#define SWAP1 0xB1   // quad_perm(1,0,3,2): xor-1 partner
#define WSHR1 0x138  // wave_shr:1 : lane j <- j-1
#define WSHL1 0x130  // wave_shl:1 : lane j <- j+1

__device__ __forceinline__ f2 b2(float s) { f2 r; r.x = s; r.y = s; return r; }
#define SW(v) __builtin_shufflevector((v), (v), 1, 0)
#define FMA2(a, b, c) __builtin_elementwise_fma((a), (b), (c))

// K1: AvP[h][rp][j] = float4 {re,im of v-row 2rp ; re,im of v-row 2rp+1}
//     (re,im)[row][j] = sum_i values[row,i] * U[h, 64+i, j]
// Block 0 additionally precomputes the per-(h,j) recurrence coefficients
// (all trig) into Coef[10][256] so k_rnn's 1024 blocks skip the lib sin/cos.
__global__ __launch_bounds__(256) void k_av(const float* __restrict__ values,
                                            const float* __restrict__ U_re,
                                            const float* __restrict__ U_im,
                                            const float* __restrict__ bias,
                                            const float* __restrict__ theta1,
                                            const float* __restrict__ phi1,
                                            const float* __restrict__ theta2,
                                            const float* __restrict__ phi2,
                                            const float* __restrict__ omega,
                                            f4* __restrict__ AvP,
                                            float* __restrict__ Coef) {
    int tid = blockIdx.x * blockDim.x + threadIdx.x;
    int w = tid >> 6;            // 0..2047
    int j = tid & 63;
    int h = w >> 9;              // 0..3
    int rp = w & 511;            // v-row pair within head
    int r0 = rp << 1;
    const float* vrow = values + r0 * DIM;                     // wave-uniform
    const float* ur = U_re + (h * 2 * DIM + DIM) * DIM + j;    // bottom half
    const float* ui = U_im + (h * 2 * DIM + DIM) * DIM + j;
    f2 a0 = 0.f, a1 = 0.f;
    #pragma unroll 8
    for (int i = 0; i < DIM; ++i) {
        f2 u; u.x = ur[i * DIM]; u.y = ui[i * DIM];
        a0 += vrow[i] * u;
        a1 += vrow[DIM + i] * u;
    }
    f4 o; o.x = a0.x; o.y = a0.y; o.z = a1.x; o.w = a1.y;
    AvP[(h * 512 + rp) * 64 + j] = o;      // one dwordx4 store

    if (blockIdx.x == 0) {
        int t = threadIdx.x;
        int hh = t >> 6, jj = t & 63;
        int k1 = jj >> 1;
        float th1 = theta1[hh * 32 + k1], ph1 = phi1[hh * 32 + k1];
        float C1 = cosf(th1), s1v = sinf(th1);
        float S1, E1r, E1i;
        if ((jj & 1) == 0) { S1 = -s1v; E1r = cosf(ph1); E1i = sinf(ph1); }
        else               { S1 =  s1v; E1r = 1.f;       E1i = 0.f;       }
        float C2, SL, SR, p2r, p2i;
        if (jj == 0 || jj == 63) {
            C2 = 1.f; SL = 0.f; SR = 0.f; p2r = 1.f; p2i = 0.f;
        } else {
            int k2 = (jj - 1) >> 1;
            float th2 = theta2[hh * 31 + k2], ph2 = phi2[hh * 31 + k2];
            float c2 = cosf(th2), s2 = sinf(th2);
            if (jj & 1) { C2 = c2; SL = -s2; SR = 0.f; p2r = cosf(ph2); p2i = sinf(ph2); }
            else        { C2 = c2; SR =  s2; SL = 0.f; p2r = 1.f;       p2i = 0.f;      }
        }
        float om = omega[hh * 64 + jj];
        float eor = cosf(om), eoi = sinf(om);
        float PHr = p2r * eor - p2i * eoi;
        float PHi = p2r * eoi + p2i * eor;
        Coef[0 * 256 + t] = C1;
        Coef[1 * 256 + t] = S1;
        Coef[2 * 256 + t] = E1r;
        Coef[3 * 256 + t] = E1i;
        Coef[4 * 256 + t] = C2;
        Coef[5 * 256 + t] = SL;
        Coef[6 * 256 + t] = SR;
        Coef[7 * 256 + t] = PHr;
        Coef[8 * 256 + t] = PHi;
        Coef[9 * 256 + t] = bias[hh * 64 + jj];
    }
}

// K2: 1024 blocks (one query row each) x 4 waves (one head each);
// launch_bounds(256,4) -> 4 blocks/CU = 4 waves/SIMD: twice the independent
// instruction streams of the row-pair version, so Av-load (L3/cross-XCD L2)
// latency and DPP hazards are covered by other waves instead of stalling the
// SIMD. Packed f2 step (v_pk_fma_f32), ~23 VALU/step. Coefficients are
// 10 coalesced loads from the precomputed table (no lib trig here).
__global__ __launch_bounds__(256, 4) void k_rnn_dense(
        const float* __restrict__ queries,
        const float* __restrict__ U_re,
        const float* __restrict__ U_im,
        const float* __restrict__ Coef,
        const f4* __restrict__ AvP,
        const float* __restrict__ W_dense,
        const float* __restrict__ b_dense,
        float* __restrict__ y) {
    int n = blockIdx.x;        // 0..1023 (query row)
    int t = threadIdx.x;
    int h = t >> 6;            // head = wave
    int j = t & 63;            // state dim = lane
    int b = n >> 7;

    // ---- coefficients: 10 coalesced loads ----
    float C1  = Coef[0 * 256 + t];
    float S1  = Coef[1 * 256 + t];
    float E1r = Coef[2 * 256 + t];
    float E1i = Coef[3 * 256 + t];
    float C2  = Coef[4 * 256 + t];
    float SL  = Coef[5 * 256 + t];
    float SR  = Coef[6 * 256 + t];
    float PHr = Coef[7 * 256 + t];
    float PHi = Coef[8 * 256 + t];
    float bj  = Coef[9 * 256 + t];

    f2 C1p = b2(C1), S1p = b2(S1), E1rp = b2(E1r);
    f2 E1in; E1in.x = -E1i; E1in.y = E1i;
    f2 C2p = b2(C2), SLp = b2(SL), SRp = b2(SR), PHrp = b2(PHr);
    f2 PHin; PHin.x = -PHi; PHin.y = PHi;

    // ---- Aq: uq = q_row . U_top[h] ----
    const float* q0 = queries + n * DIM;         // block-uniform
    const float* ur = U_re + (h * 2 * DIM) * DIM + j;
    const float* ui = U_im + (h * 2 * DIM) * DIM + j;
    f2 uq = 0.f;
    #pragma unroll 8
    for (int i = 0; i < DIM; ++i) {
        f2 u; u.x = ur[i * DIM]; u.y = ui[i * DIM];
        uq = FMA2(b2(q0[i]), u, uq);
    }

    f2 hS = 0.f;
    // packed step: identical op sequence to the verified scalar chain
    auto step = [&](f2 av) {
        f2 uv = uq + av;
        f2 p; p.x = dppf<SWAP1>(hS.x); p.y = dppf<SWAP1>(hS.y);
        f2 tp = FMA2(C1p, hS, S1p * p);
        f2 T  = FMA2(E1rp, tp, E1in * SW(tp));
        f2 L; L.x = dppf<WSHL1>(T.x); L.y = dppf<WSHL1>(T.y);
        f2 R; R.x = dppf<WSHR1>(T.x); R.y = dppf<WSHR1>(T.y);
        f2 sp = FMA2(C2p, T, FMA2(SLp, L, SRp * R));
        f2 z  = FMA2(PHrp, sp, FMA2(PHin, SW(sp), uv));
        float q2 = fmaf(z.x, z.x, fmaf(z.y, z.y, 1e-10f));
        float rs = __builtin_amdgcn_rsqf(q2);
        float sc = fmaxf(fmaf(bj, rs, 1.f), 0.f);
        hS = z * b2(sc);
    };

    // ---- scan: 64 timestep-pairs (f4 = 2 steps), batch-4 register dbuf ----
    const f4* p = AvP + (h * 512 + b * 64) * 64 + j;   // pair stride = 64 f4
    f4 buf[4], nxt[4];
    #pragma unroll
    for (int k = 0; k < 4; ++k) buf[k] = p[k * 64];

    for (int w = 0; w < 16; ++w) {
        const f4* pn = p + ((w < 15) ? 4 * 64 : 0);
        #pragma unroll
        for (int k = 0; k < 4; ++k) nxt[k] = pn[k * 64];
        p = pn;
        #pragma unroll
        for (int k = 0; k < 4; ++k) {
            f2 a; a.x = buf[k].x; a.y = buf[k].y;
            step(a);                       // timestep 2k
            f2 c; c.x = buf[k].z; c.y = buf[k].w;
            step(c);                       // timestep 2k+1
        }
        #pragma unroll
        for (int k = 0; k < 4; ++k) buf[k] = nxt[k];
    }

    // ---- fused dense for row n ----
    __shared__ float s_acc[HEADS * DIM];   // 256
    __shared__ float s_part[256];
    s_acc[h * 64 + j] = hS.x;              // Re(hT)
    __syncthreads();

    {   // thread t: k-quarter qq = t>>6, col jj = t&63
        int qq = t >> 6, jj = t & 63;
        const float* Wp = W_dense + (qq * 64) * DIM + jj;
        const float* ap = &s_acc[qq * 64];
        float part = 0.f;
        #pragma unroll 8
        for (int k = 0; k < 64; ++k)
            part = fmaf(ap[k], Wp[k * DIM], part);   // ap broadcast, Wp coalesced
        s_part[t] = part;
    }
    __syncthreads();
    if (t < 64) {
        y[n * DIM + t] = b_dense[t] + s_part[t] + s_part[64 + t]
                       + s_part[128 + t] + s_part[192 + t];
    }
}

extern "C" void kernel_launch(void* const* d_in, const int* in_sizes, int n_in,
                              void* d_out, int out_size, void* d_ws, size_t ws_size,
                              hipStream_t stream) {
    const float* queries = (const float*)d_in[0];
    const float* values  = (const float*)d_in[1];
    const float* U_re    = (const float*)d_in[2];
    const float* U_im    = (const float*)d_in[3];
    const float* bias    = (const float*)d_in[4];
    const float* theta1  = (const float*)d_in[5];
    const float* phi1    = (const float*)d_in[6];
    const float* theta2  = (const float*)d_in[7];
    const float* phi2    = (const float*)d_in[8];
    const float* omega   = (const float*)d_in[9];
    const float* W_dense = (const float*)d_in[10];
    const float* b_dense = (const float*)d_in[11];
    float* y = (float*)d_out;

    f4* AvP = (f4*)d_ws;                              // 2 MB
    float* Coef = (float*)((char*)d_ws + HEADS * 512 * 64 * sizeof(f4));  // 10 KB

    k_av<<<512, 256, 0, stream>>>(values, U_re, U_im, bias, theta1, phi1,
                                  theta2, phi2, omega, AvP, Coef);
    k_rnn_dense<<<1024, 256, 0, stream>>>(queries, U_re, U_im, Coef, AvP,
                                          W_dense, b_dense, y);
}